// Round 1
// baseline (197.144 us; speedup 1.0000x reference)
//
#include <hip/hip_runtime.h>

// Problem constants (fixed by the reference)
#define BB    4
#define TE    1024
#define TD    512
#define HH    128
#define H4    32            // H/4
#define TTILE 64            // t-positions staged per LDS tile
#define DTILE 4             // decoder steps per block (one per wave)
#define LDSW  132           // LDS row stride in words (128 + 4 pad, 16B-aligned)

__device__ __forceinline__ float fast_tanh(float x) {
    // tanh(x) = 1 - 2/(exp(2x)+1); v_exp + v_rcp, ~1e-6 rel error.
    float ex = __expf(2.0f * x);
    float r  = __builtin_amdgcn_rcpf(ex + 1.0f);
    return 1.0f - 2.0f * r;
}

// ---------------------------------------------------------------------------
// Kernel 1: fused projections. Rows [0, B*TE) = enc @ W_a, rows [B*TE, ..) =
// dec @ U_a. 2 rows per 256-thread block; X[r][k] is wave-uniform (L1
// broadcast), W[k][c] coalesced across the 128 c-threads.
// ---------------------------------------------------------------------------
__global__ __launch_bounds__(256) void proj_gemm(
    const float* __restrict__ enc,   // [B*TE, H]
    const float* __restrict__ dec,   // [B*TD, H]
    const float* __restrict__ Wa,    // [H, H]
    const float* __restrict__ Ua,    // [H, H]
    float* __restrict__ out)         // [B*TE + B*TD, H]
{
    const int c  = threadIdx.x & 127;
    const int rr = threadIdx.x >> 7;
    const int r  = blockIdx.x * 2 + rr;

    const float* X;
    const float* W;
    int rX;
    if (r < BB * TE) { X = enc; W = Wa; rX = r; }
    else             { X = dec; W = Ua; rX = r - BB * TE; }

    const float* xrow = X + rX * HH;
    float acc = 0.f;
    #pragma unroll
    for (int k = 0; k < HH; k += 4) {
        float4 xv = *(const float4*)(xrow + k);
        acc += xv.x * W[(k + 0) * HH + c];
        acc += xv.y * W[(k + 1) * HH + c];
        acc += xv.z * W[(k + 2) * HH + c];
        acc += xv.w * W[(k + 3) * HH + c];
    }
    out[r * HH + c] = acc;
}

// ---------------------------------------------------------------------------
// Kernel 2: fused energies -> softmax -> context.
// Grid: (B*TD)/DTILE = 512 blocks, 256 threads (4 waves). Wave w owns decoder
// step d0+w. LDS: 64x128 fp32 tile (stride-132 rows), U_h rows, V, e-rows.
// ---------------------------------------------------------------------------
__global__ __launch_bounds__(256) void attn_fused(
    const float* __restrict__ enc,    // [B, TE, H]
    const float* __restrict__ ws,     // [B*TE, H]  (W_s)
    const float* __restrict__ uh,     // [B*TD, H]  (U_h)
    const float* __restrict__ Va,     // [H]
    float* __restrict__ c_out,        // [B, TD, H]
    float* __restrict__ e_out)        // [B, TD, TE]
{
    __shared__ float tile[TTILE * LDSW];     // 33792 B (W_s tiles, then enc tiles)
    __shared__ float uh_s[DTILE * HH];       //  2048 B
    __shared__ float v_s[HH];                //   512 B
    __shared__ float e_s[DTILE * TE];        // 16384 B

    const int tid  = threadIdx.x;
    const int lane = tid & 63;
    const int wid  = tid >> 6;                       // wave id == local d
    const int blk  = blockIdx.x;
    const int b    = blk / (TD / DTILE);
    const int d0   = (blk % (TD / DTILE)) * DTILE;

    // Stage V and the 4 U_h rows.
    if (tid < HH) v_s[tid] = Va[tid];
    {
        const float4* src = (const float4*)(uh + (b * TD + d0) * HH);
        float4*       dst = (float4*)uh_s;
        if (tid < DTILE * H4) dst[tid] = src[tid];
    }

    const float* ws_b   = ws + (size_t)b * TE * HH;
    const float* uh_row = uh_s + wid * HH;

    // ---------------- Phase 1: energies ----------------
    for (int tt = 0; tt < TE / TTILE; ++tt) {
        // Cooperative load of 64x128 W_s tile (2048 float4, 8 per thread).
        const float4* src = (const float4*)(ws_b + tt * TTILE * HH);
        #pragma unroll
        for (int i = 0; i < 8; ++i) {
            int idx = tid + i * 256;
            int row = idx >> 5;
            int col = idx & 31;
            *(float4*)&tile[row * LDSW + col * 4] = src[idx];
        }
        __syncthreads();

        // lane -> t within tile; wave -> d. 32 float4 h-steps.
        float acc = 0.f;
        const float* wrow = tile + lane * LDSW;
        #pragma unroll 8
        for (int h4 = 0; h4 < H4; ++h4) {
            float4 w = *(const float4*)&wrow[h4 * 4];
            float4 u = *(const float4*)&uh_row[h4 * 4];   // wave-uniform (broadcast)
            float4 v = *(const float4*)&v_s[h4 * 4];      // wave-uniform (broadcast)
            acc += v.x * fast_tanh(w.x + u.x)
                 + v.y * fast_tanh(w.y + u.y)
                 + v.z * fast_tanh(w.z + u.z)
                 + v.w * fast_tanh(w.w + u.w);
        }
        e_s[wid * TE + tt * TTILE + lane] = acc;
        __syncthreads();   // tile reused next iteration
    }

    // ---------------- Phase 2: softmax (per-wave, private row) ----------------
    {
        float* row = e_s + wid * TE;
        float m = -1e30f;
        #pragma unroll
        for (int i = 0; i < TE / 64; ++i) m = fmaxf(m, row[lane + i * 64]);
        #pragma unroll
        for (int off = 32; off > 0; off >>= 1) m = fmaxf(m, __shfl_xor(m, off));

        float vals[TE / 64];
        float s = 0.f;
        #pragma unroll
        for (int i = 0; i < TE / 64; ++i) {
            vals[i] = __expf(row[lane + i * 64] - m);
            s += vals[i];
        }
        #pragma unroll
        for (int off = 32; off > 0; off >>= 1) s += __shfl_xor(s, off);
        float inv = __builtin_amdgcn_rcpf(s);

        float* eo = e_out + (size_t)(b * TD + d0 + wid) * TE;
        #pragma unroll
        for (int i = 0; i < TE / 64; ++i) {
            float p = vals[i] * inv;
            row[lane + i * 64] = p;     // keep for context phase
            eo[lane + i * 64]  = p;     // coalesced global write
        }
    }

    // ---------------- Phase 3: context c[b,d,:] = sum_t e * enc[b,t,:] -------
    const float* enc_b = enc + (size_t)b * TE * HH;
    const int th = lane >> 5;     // which half of the t-tile
    const int h4 = lane & 31;     // which float4 of the H row
    float4 acc4 = make_float4(0.f, 0.f, 0.f, 0.f);

    for (int tt = 0; tt < TE / TTILE; ++tt) {
        __syncthreads();          // tile reuse fence
        const float4* src = (const float4*)(enc_b + tt * TTILE * HH);
        #pragma unroll
        for (int i = 0; i < 8; ++i) {
            int idx = tid + i * 256;
            int row = idx >> 5;
            int col = idx & 31;
            *(float4*)&tile[row * LDSW + col * 4] = src[idx];
        }
        __syncthreads();

        const float* erow = e_s + wid * TE + tt * TTILE + th * 32;
        #pragma unroll 8
        for (int t = 0; t < 32; ++t) {
            float  w  = erow[t];   // 2-address broadcast per wave
            float4 ev = *(const float4*)&tile[(th * 32 + t) * LDSW + h4 * 4];
            acc4.x += w * ev.x;
            acc4.y += w * ev.y;
            acc4.z += w * ev.z;
            acc4.w += w * ev.w;
        }
    }

    // Combine the two t-halves across lane^32, lanes 0..31 write.
    acc4.x += __shfl_xor(acc4.x, 32);
    acc4.y += __shfl_xor(acc4.y, 32);
    acc4.z += __shfl_xor(acc4.z, 32);
    acc4.w += __shfl_xor(acc4.w, 32);
    if (th == 0) {
        float4* co = (float4*)(c_out + (size_t)(b * TD + d0 + wid) * HH);
        co[h4] = acc4;
    }
}

// ---------------------------------------------------------------------------
extern "C" void kernel_launch(void* const* d_in, const int* in_sizes, int n_in,
                              void* d_out, int out_size, void* d_ws, size_t ws_size,
                              hipStream_t stream) {
    (void)in_sizes; (void)n_in; (void)out_size; (void)ws_size;

    const float* enc = (const float*)d_in[0];   // [B,TE,H]
    const float* dec = (const float*)d_in[1];   // [B,TD,H]
    const float* Wa  = (const float*)d_in[2];   // [H,H]
    const float* Ua  = (const float*)d_in[3];   // [H,H]
    const float* Va  = (const float*)d_in[4];   // [H,1] -> [H]

    float* c_out = (float*)d_out;                         // B*TD*H = 262144
    float* e_out = (float*)d_out + BB * TD * HH;          // B*TD*TE = 2097152

    float* proj = (float*)d_ws;                           // (B*TE + B*TD)*H floats = 3 MB
    float* ws_p = proj;                                   // W_s: [B*TE, H]
    float* uh_p = proj + BB * TE * HH;                    // U_h: [B*TD, H]

    proj_gemm<<<(BB * TE + BB * TD) / 2, 256, 0, stream>>>(enc, dec, Wa, Ua, proj);
    attn_fused<<<(BB * TD) / DTILE, 256, 0, stream>>>(enc, ws_p, uh_p, Va, c_out, e_out);
}

// Round 2
// 161.192 us; speedup vs baseline: 1.2230x; 1.2230x over previous
//
#include <hip/hip_runtime.h>

#define BB    4
#define TE    1024
#define TD    512
#define HH    128
#define DTILE 4
#define TTILE 64
#define C2    2.8853900817779268f   // 2*log2(e); proj pre-scales W_s and U_h by this
#define LOG2E 1.4426950408889634f

// Async global->LDS, 16B per lane. LDS dest = wave-uniform base + lane*16.
__device__ __forceinline__ void gload16_lds(const float* g, float* l) {
    __builtin_amdgcn_global_load_lds(
        (const __attribute__((address_space(1))) unsigned int*)g,
        (__attribute__((address_space(3))) unsigned int*)l, 16, 0, 0);
}

__device__ __forceinline__ float sigsum4(float4 wv, float4 cu, float4 v, float acc) {
    // acc += sum_i v_i * 1/(1 + 2^(wv_i + cu_i))   [inputs pre-scaled by C2]
    acc = fmaf(v.x, __builtin_amdgcn_rcpf(1.0f + __builtin_amdgcn_exp2f(wv.x + cu.x)), acc);
    acc = fmaf(v.y, __builtin_amdgcn_rcpf(1.0f + __builtin_amdgcn_exp2f(wv.y + cu.y)), acc);
    acc = fmaf(v.z, __builtin_amdgcn_rcpf(1.0f + __builtin_amdgcn_exp2f(wv.z + cu.z)), acc);
    acc = fmaf(v.w, __builtin_amdgcn_rcpf(1.0f + __builtin_amdgcn_exp2f(wv.w + cu.w)), acc);
    return acc;
}

// ---------------------------------------------------------------------------
// Kernel 1: tiled projections, output pre-scaled by C2.
// Block = 64 rows x 64 cols; thread = 4 rows x 4 cols. Grid 192.
// ---------------------------------------------------------------------------
__global__ __launch_bounds__(256) void proj_gemm(
    const float* __restrict__ enc, const float* __restrict__ dec,
    const float* __restrict__ Wa,  const float* __restrict__ Ua,
    float* __restrict__ out)
{
    __shared__ float Xs[64 * 33];   // 64 rows x 32 k (+1 pad)
    __shared__ float Ws[32 * 64];   // 32 k x 64 cols

    const int tid = threadIdx.x;
    const int rt = blockIdx.x >> 1, ch = blockIdx.x & 1;
    const int r0 = rt * 64, c0 = ch * 64;

    const float* X; const float* W; int rX0;
    if (r0 < BB * TE) { X = enc; W = Wa; rX0 = r0; }
    else              { X = dec; W = Ua; rX0 = r0 - BB * TE; }

    const int c4 = tid & 15;        // col float4 (16 x 4 = 64 cols)
    const int rg = tid >> 4;        // row group (16 x 4 = 64 rows)

    float4 a0 = {0,0,0,0}, a1 = a0, a2 = a0, a3 = a0;

    for (int kc = 0; kc < 4; ++kc) {
        #pragma unroll
        for (int i = 0; i < 2; ++i) {
            int idx = tid + i * 256;
            int r  = idx >> 3, k4 = idx & 7;
            *(float4*)&Xs[r * 33 + k4 * 4] =
                *(const float4*)&X[(rX0 + r) * HH + kc * 32 + k4 * 4];
            int kk = idx >> 4, cc = idx & 15;
            *(float4*)&Ws[kk * 64 + cc * 4] =
                *(const float4*)&W[(kc * 32 + kk) * HH + c0 + cc * 4];
        }
        __syncthreads();
        #pragma unroll 8
        for (int k = 0; k < 32; ++k) {
            float4 wv = *(const float4*)&Ws[k * 64 + c4 * 4];
            float x0 = Xs[(rg * 4 + 0) * 33 + k];
            float x1 = Xs[(rg * 4 + 1) * 33 + k];
            float x2 = Xs[(rg * 4 + 2) * 33 + k];
            float x3 = Xs[(rg * 4 + 3) * 33 + k];
            a0.x = fmaf(x0, wv.x, a0.x); a0.y = fmaf(x0, wv.y, a0.y);
            a0.z = fmaf(x0, wv.z, a0.z); a0.w = fmaf(x0, wv.w, a0.w);
            a1.x = fmaf(x1, wv.x, a1.x); a1.y = fmaf(x1, wv.y, a1.y);
            a1.z = fmaf(x1, wv.z, a1.z); a1.w = fmaf(x1, wv.w, a1.w);
            a2.x = fmaf(x2, wv.x, a2.x); a2.y = fmaf(x2, wv.y, a2.y);
            a2.z = fmaf(x2, wv.z, a2.z); a2.w = fmaf(x2, wv.w, a2.w);
            a3.x = fmaf(x3, wv.x, a3.x); a3.y = fmaf(x3, wv.y, a3.y);
            a3.z = fmaf(x3, wv.z, a3.z); a3.w = fmaf(x3, wv.w, a3.w);
        }
        __syncthreads();
    }

    float4 accs[4] = {a0, a1, a2, a3};
    #pragma unroll
    for (int j = 0; j < 4; ++j) {
        float4 o = accs[j];
        o.x *= C2; o.y *= C2; o.z *= C2; o.w *= C2;
        *(float4*)&out[(r0 + rg * 4 + j) * HH + c0 + c4 * 4] = o;
    }
}

// ---------------------------------------------------------------------------
// Kernel 2: fused energies -> softmax -> context.
// Grid 512 blocks x 512 threads (8 waves). d = w&3, tq = w>>2 (t-half).
// Tile: 64x128 fp32, XOR-swizzled 16B chunks (global_load_lds compatible,
// conflict-free b128 reads). cu (=C2*U_h) and v held in registers per lane.
// ---------------------------------------------------------------------------
__global__ __launch_bounds__(512, 4) void attn_fused(
    const float* __restrict__ enc,    // [B, TE, H] raw
    const float* __restrict__ ws,     // [B*TE, H]  = C2 * W_s
    const float* __restrict__ uh,     // [B*TD, H]  = C2 * U_h
    const float* __restrict__ Va,     // [H]
    float* __restrict__ c_out,        // [B, TD, H]
    float* __restrict__ e_out)        // [B, TD, TE]
{
    __shared__ float tile[TTILE * HH];   // 32 KB
    __shared__ float e_s[DTILE * TE];    // 16 KB
    __shared__ float cu_s[DTILE * HH];   //  2 KB
    __shared__ float c_s[DTILE * HH];    //  2 KB

    const int tid = threadIdx.x;
    const int l   = tid & 63;
    const int w   = tid >> 6;            // 0..7
    const int b   = blockIdx.x >> 7;
    const int d0  = (blockIdx.x & 127) * DTILE;
    const int d   = w & 3;
    const int tq  = w >> 2;

    if (tid < DTILE * HH) cu_s[tid] = uh[((size_t)b * TD + d0) * HH + tid];
    __syncthreads();

    // Per-lane register fragments: 16 h-values each of cu and v.
    const int hs = l >> 3;               // h-chunk (8 x 16)
    const int r8 = l & 7;                // row within pass
    float4 cu4[4], v4[4];
    #pragma unroll
    for (int j = 0; j < 4; ++j) {
        cu4[j] = *(const float4*)&cu_s[d * HH + hs * 16 + j * 4];
        v4[j]  = *(const float4*)&Va[hs * 16 + j * 4];
    }
    float Vsum = 0.f;
    #pragma unroll
    for (int j = 0; j < 4; ++j) Vsum += v4[j].x + v4[j].y + v4[j].z + v4[j].w;
    Vsum += __shfl_xor(Vsum, 8);
    Vsum += __shfl_xor(Vsum, 16);
    Vsum += __shfl_xor(Vsum, 32);

    // Staging constants (4 instrs/wave/tile, 2 rows each, XOR-swizzled source)
    int offg[4]; int offl[4];
    #pragma unroll
    for (int i = 0; i < 4; ++i) {
        int row = w * 8 + i * 2 + (l >> 5);
        int gch = (l & 31) ^ (row & 7);
        offg[i] = row * HH + gch * 4;
        offl[i] = (w * 8 + i * 2) * HH;  // wave-uniform
    }
    const float* ws_b  = ws  + (size_t)b * TE * HH;
    const float* enc_b = enc + (size_t)b * TE * HH;

    // ---------------- Phase 1: energies ----------------
    for (int tt = 0; tt < TE / TTILE; ++tt) {
        const float* src = ws_b + tt * TTILE * HH;
        #pragma unroll
        for (int i = 0; i < 4; ++i) gload16_lds(src + offg[i], &tile[offl[i]]);
        __syncthreads();

        #pragma unroll
        for (int p = 0; p < 4; ++p) {
            const int row = tq * 32 + p * 8 + r8;
            const int key = row & 7;
            float acc = 0.f;
            #pragma unroll
            for (int j = 0; j < 4; ++j) {
                const int q = hs * 4 + j;
                float4 wv = *(const float4*)&tile[row * HH + (q ^ key) * 4];
                acc = sigsum4(wv, cu4[j], v4[j], acc);
            }
            acc += __shfl_xor(acc, 8);
            acc += __shfl_xor(acc, 16);
            acc += __shfl_xor(acc, 32);
            if (l < 8) e_s[d * TE + tt * TTILE + row] = Vsum - 2.f * acc;
        }
        __syncthreads();
    }

    // ---------------- Phase 2: softmax (redundant per tq-pair) ----------------
    {
        float ev[16];
        float m = -3.0e38f;
        #pragma unroll
        for (int i = 0; i < 16; ++i) {
            ev[i] = e_s[d * TE + i * 64 + l];
            m = fmaxf(m, ev[i]);
        }
        #pragma unroll
        for (int off = 32; off; off >>= 1) m = fmaxf(m, __shfl_xor(m, off));
        float s = 0.f;
        #pragma unroll
        for (int i = 0; i < 16; ++i) {
            ev[i] = __builtin_amdgcn_exp2f((ev[i] - m) * LOG2E);
            s += ev[i];
        }
        #pragma unroll
        for (int off = 32; off; off >>= 1) s += __shfl_xor(s, off);
        float inv = __builtin_amdgcn_rcpf(s);
        float* eo = e_out + ((size_t)b * TD + d0 + d) * TE;
        #pragma unroll
        for (int i = 0; i < 8; ++i) {
            int ii = tq * 8 + i;
            float p = ev[ii] * inv;
            e_s[d * TE + ii * 64 + l] = p;
            eo[ii * 64 + l] = p;
        }
    }

    // ---------------- Phase 3: context ----------------
    const int h4 = l & 31, tsub = l >> 5;
    float4 acc = {0.f, 0.f, 0.f, 0.f};
    for (int tt = 0; tt < TE / TTILE; ++tt) {
        const float* src = enc_b + tt * TTILE * HH;
        #pragma unroll
        for (int i = 0; i < 4; ++i) gload16_lds(src + offg[i], &tile[offl[i]]);
        __syncthreads();

        const float* erow = &e_s[d * TE + tt * TTILE + tq * 32 + tsub * 16];
        #pragma unroll
        for (int k = 0; k < 16; ++k) {
            const int row = tq * 32 + tsub * 16 + k;
            float p = erow[k];
            float4 x = *(const float4*)&tile[row * HH + ((h4 ^ (row & 7))) * 4];
            acc.x = fmaf(p, x.x, acc.x);
            acc.y = fmaf(p, x.y, acc.y);
            acc.z = fmaf(p, x.z, acc.z);
            acc.w = fmaf(p, x.w, acc.w);
        }
        __syncthreads();
    }

    acc.x += __shfl_xor(acc.x, 32);
    acc.y += __shfl_xor(acc.y, 32);
    acc.z += __shfl_xor(acc.z, 32);
    acc.w += __shfl_xor(acc.w, 32);

    if (tq == 0 && tsub == 0) *(float4*)&c_s[d * HH + h4 * 4] = acc;
    __syncthreads();
    if (tq == 1 && tsub == 0) {
        float4 o = *(const float4*)&c_s[d * HH + h4 * 4];
        o.x += acc.x; o.y += acc.y; o.z += acc.z; o.w += acc.w;
        *(float4*)&c_s[d * HH + h4 * 4] = o;
    }
    __syncthreads();
    c_out[((size_t)b * TD + d0) * HH + tid] = c_s[tid];
}

// ---------------------------------------------------------------------------
extern "C" void kernel_launch(void* const* d_in, const int* in_sizes, int n_in,
                              void* d_out, int out_size, void* d_ws, size_t ws_size,
                              hipStream_t stream) {
    (void)in_sizes; (void)n_in; (void)out_size; (void)ws_size;

    const float* enc = (const float*)d_in[0];   // [B,TE,H]
    const float* dec = (const float*)d_in[1];   // [B,TD,H]
    const float* Wa  = (const float*)d_in[2];   // [H,H]
    const float* Ua  = (const float*)d_in[3];   // [H,H]
    const float* Va  = (const float*)d_in[4];   // [H,1]

    float* c_out = (float*)d_out;                       // B*TD*H
    float* e_out = (float*)d_out + BB * TD * HH;        // B*TD*TE

    float* proj = (float*)d_ws;                         // (B*TE + B*TD)*H floats
    float* ws_p = proj;                                 // C2*W_s: [B*TE, H]
    float* uh_p = proj + BB * TE * HH;                  // C2*U_h: [B*TD, H]

    proj_gemm<<<192, 256, 0, stream>>>(enc, dec, Wa, Ua, proj);
    attn_fused<<<(BB * TD) / DTILE, 512, 0, stream>>>(enc, ws_p, uh_p, Va, c_out, e_out);
}

// Round 3
// 154.153 us; speedup vs baseline: 1.2789x; 1.0457x over previous
//
#include <hip/hip_runtime.h>

#define BB    4
#define TE    1024
#define TD    512
#define HH    128
#define DTILE 4
#define TTILE 64
#define C2    2.8853900817779268f   // 2*log2(e); proj pre-scales W_s and U_h by this
#define LOG2E 1.4426950408889634f

// Async global->LDS, 16B per lane. LDS dest = wave-uniform base + lane*16.
__device__ __forceinline__ void gload16_lds(const float* g, float* l) {
    __builtin_amdgcn_global_load_lds(
        (const __attribute__((address_space(1))) unsigned int*)g,
        (__attribute__((address_space(3))) unsigned int*)l, 16, 0, 0);
}

__device__ __forceinline__ float sigsum4(float4 wv, float4 cu, float4 v, float acc) {
    // acc += sum_i v_i * 1/(1 + 2^(wv_i + cu_i))   [inputs pre-scaled by C2]
    acc = fmaf(v.x, __builtin_amdgcn_rcpf(1.0f + __builtin_amdgcn_exp2f(wv.x + cu.x)), acc);
    acc = fmaf(v.y, __builtin_amdgcn_rcpf(1.0f + __builtin_amdgcn_exp2f(wv.y + cu.y)), acc);
    acc = fmaf(v.z, __builtin_amdgcn_rcpf(1.0f + __builtin_amdgcn_exp2f(wv.z + cu.z)), acc);
    acc = fmaf(v.w, __builtin_amdgcn_rcpf(1.0f + __builtin_amdgcn_exp2f(wv.w + cu.w)), acc);
    return acc;
}

// ---------------------------------------------------------------------------
// Kernel 1: tiled projections, output pre-scaled by C2 (unchanged from R2).
// ---------------------------------------------------------------------------
__global__ __launch_bounds__(256) void proj_gemm(
    const float* __restrict__ enc, const float* __restrict__ dec,
    const float* __restrict__ Wa,  const float* __restrict__ Ua,
    float* __restrict__ out)
{
    __shared__ float Xs[64 * 33];
    __shared__ float Ws[32 * 64];

    const int tid = threadIdx.x;
    const int rt = blockIdx.x >> 1, ch = blockIdx.x & 1;
    const int r0 = rt * 64, c0 = ch * 64;

    const float* X; const float* W; int rX0;
    if (r0 < BB * TE) { X = enc; W = Wa; rX0 = r0; }
    else              { X = dec; W = Ua; rX0 = r0 - BB * TE; }

    const int c4 = tid & 15;
    const int rg = tid >> 4;

    float4 a0 = {0,0,0,0}, a1 = a0, a2 = a0, a3 = a0;

    for (int kc = 0; kc < 4; ++kc) {
        #pragma unroll
        for (int i = 0; i < 2; ++i) {
            int idx = tid + i * 256;
            int r  = idx >> 3, k4 = idx & 7;
            *(float4*)&Xs[r * 33 + k4 * 4] =
                *(const float4*)&X[(rX0 + r) * HH + kc * 32 + k4 * 4];
            int kk = idx >> 4, cc = idx & 15;
            *(float4*)&Ws[kk * 64 + cc * 4] =
                *(const float4*)&W[(kc * 32 + kk) * HH + c0 + cc * 4];
        }
        __syncthreads();
        #pragma unroll 8
        for (int k = 0; k < 32; ++k) {
            float4 wv = *(const float4*)&Ws[k * 64 + c4 * 4];
            float x0 = Xs[(rg * 4 + 0) * 33 + k];
            float x1 = Xs[(rg * 4 + 1) * 33 + k];
            float x2 = Xs[(rg * 4 + 2) * 33 + k];
            float x3 = Xs[(rg * 4 + 3) * 33 + k];
            a0.x = fmaf(x0, wv.x, a0.x); a0.y = fmaf(x0, wv.y, a0.y);
            a0.z = fmaf(x0, wv.z, a0.z); a0.w = fmaf(x0, wv.w, a0.w);
            a1.x = fmaf(x1, wv.x, a1.x); a1.y = fmaf(x1, wv.y, a1.y);
            a1.z = fmaf(x1, wv.z, a1.z); a1.w = fmaf(x1, wv.w, a1.w);
            a2.x = fmaf(x2, wv.x, a2.x); a2.y = fmaf(x2, wv.y, a2.y);
            a2.z = fmaf(x2, wv.z, a2.z); a2.w = fmaf(x2, wv.w, a2.w);
            a3.x = fmaf(x3, wv.x, a3.x); a3.y = fmaf(x3, wv.y, a3.y);
            a3.z = fmaf(x3, wv.z, a3.z); a3.w = fmaf(x3, wv.w, a3.w);
        }
        __syncthreads();
    }

    float4 accs[4] = {a0, a1, a2, a3};
    #pragma unroll
    for (int j = 0; j < 4; ++j) {
        float4 o = accs[j];
        o.x *= C2; o.y *= C2; o.z *= C2; o.w *= C2;
        *(float4*)&out[(r0 + rg * 4 + j) * HH + c0 + c4 * 4] = o;
    }
}

// ---------------------------------------------------------------------------
// Kernel 2: fused energies -> softmax -> context.
// Grid 512 x 512 threads (8 waves). Each wave owns a row-octet of the 64-row
// tile and computes ALL 4 d's per LDS read (cu4/v4 register-resident):
// phase-1/3 tile reads amortized 4x vs R2.
// ---------------------------------------------------------------------------
__global__ __launch_bounds__(512, 4) void attn_fused(
    const float* __restrict__ enc,    // [B, TE, H] raw
    const float* __restrict__ ws,     // [B*TE, H]  = C2 * W_s
    const float* __restrict__ uh,     // [B*TD, H]  = C2 * U_h
    const float* __restrict__ Va,     // [H]
    float* __restrict__ c_out,        // [B, TD, H]
    float* __restrict__ e_out)        // [B, TD, TE]
{
    __shared__ float tile[TTILE * HH];        // 32 KB
    __shared__ float e_s[DTILE * TE];         // 16 KB
    __shared__ float cu_s[DTILE * HH];        //  2 KB
    __shared__ float c_red[8 * DTILE * HH];   // 16 KB

    const int tid = threadIdx.x;
    const int l   = tid & 63;
    const int w   = tid >> 6;            // 0..7 (row-octet)
    const int b   = blockIdx.x >> 7;
    const int d0  = (blockIdx.x & 127) * DTILE;

    if (tid < DTILE * HH) cu_s[tid] = uh[((size_t)b * TD + d0) * HH + tid];
    __syncthreads();

    const int c8 = l & 7;                // chunk selector / reduce dim
    const int r8 = l >> 3;               // row within octet

    // Register fragments: lane covers h-chunks {j*8+c8 : j=0..3} (16 floats/d)
    float4 cu4[DTILE][4], v4[4];
    #pragma unroll
    for (int j = 0; j < 4; ++j) {
        v4[j] = *(const float4*)&Va[(j * 8 + c8) * 4];
        #pragma unroll
        for (int d = 0; d < DTILE; ++d)
            cu4[d][j] = *(const float4*)&cu_s[d * HH + (j * 8 + c8) * 4];
    }
    float Vsum = 0.f;
    #pragma unroll
    for (int j = 0; j < 4; ++j) Vsum += v4[j].x + v4[j].y + v4[j].z + v4[j].w;
    Vsum += __shfl_xor(Vsum, 1);
    Vsum += __shfl_xor(Vsum, 2);
    Vsum += __shfl_xor(Vsum, 4);

    const float* ws_b  = ws  + (size_t)b * TE * HH;
    const float* enc_b = enc + (size_t)b * TE * HH;
    const int row = w * 8 + r8;

    // ---------------- Phase 1: energies ----------------
    for (int tt = 0; tt < TE / TTILE; ++tt) {
        const float* src = ws_b + tt * TTILE * HH;
        #pragma unroll
        for (int i = 0; i < 4; ++i)
            gload16_lds(src + (w * 4 + i) * 256 + l * 4, &tile[(w * 4 + i) * 256]);
        __syncthreads();

        float acc[DTILE] = {0.f, 0.f, 0.f, 0.f};
        #pragma unroll
        for (int j = 0; j < 4; ++j) {
            float4 wv = *(const float4*)&tile[row * HH + (j * 8 + c8) * 4];
            #pragma unroll
            for (int d = 0; d < DTILE; ++d)
                acc[d] = sigsum4(wv, cu4[d][j], v4[j], acc[d]);
        }
        #pragma unroll
        for (int d = 0; d < DTILE; ++d) {
            acc[d] += __shfl_xor(acc[d], 1);
            acc[d] += __shfl_xor(acc[d], 2);
            acc[d] += __shfl_xor(acc[d], 4);
        }
        if (c8 == 0) {
            #pragma unroll
            for (int d = 0; d < DTILE; ++d)
                e_s[d * TE + tt * TTILE + row] = Vsum - 2.f * acc[d];
        }
        __syncthreads();
    }

    // ---------------- Phase 2: softmax (d = w&3, two waves redundant) --------
    {
        const int d2 = w & 3, hf = w >> 2;
        float ev[16];
        float m = -3.0e38f;
        #pragma unroll
        for (int i = 0; i < 16; ++i) {
            ev[i] = e_s[d2 * TE + i * 64 + l];
            m = fmaxf(m, ev[i]);
        }
        #pragma unroll
        for (int off = 32; off; off >>= 1) m = fmaxf(m, __shfl_xor(m, off));
        float s = 0.f;
        #pragma unroll
        for (int i = 0; i < 16; ++i) {
            ev[i] = __builtin_amdgcn_exp2f((ev[i] - m) * LOG2E);
            s += ev[i];
        }
        #pragma unroll
        for (int off = 32; off; off >>= 1) s += __shfl_xor(s, off);
        float inv = __builtin_amdgcn_rcpf(s);

        __syncthreads();   // all raw-energy reads done before overwrite
        float* eo = e_out + ((size_t)b * TD + d0 + d2) * TE;
        #pragma unroll
        for (int i = 0; i < 8; ++i) {
            int ii = hf * 8 + i;
            float p = ev[ii] * inv;
            e_s[d2 * TE + ii * 64 + l] = p;
            eo[ii * 64 + l] = p;
        }
        __syncthreads();
    }

    // ---------------- Phase 3: context (amortized across d) ------------------
    const int h4 = l & 31, tsub = l >> 5;
    float4 acc4[DTILE];
    #pragma unroll
    for (int d = 0; d < DTILE; ++d) acc4[d] = make_float4(0.f, 0.f, 0.f, 0.f);

    for (int tt = 0; tt < TE / TTILE; ++tt) {
        const float* src = enc_b + tt * TTILE * HH;
        #pragma unroll
        for (int i = 0; i < 4; ++i)
            gload16_lds(src + (w * 4 + i) * 256 + l * 4, &tile[(w * 4 + i) * 256]);
        __syncthreads();

        float4 ep[DTILE];
        #pragma unroll
        for (int d = 0; d < DTILE; ++d)
            ep[d] = *(const float4*)&e_s[d * TE + tt * TTILE + w * 8 + tsub * 4];

        #pragma unroll
        for (int k = 0; k < 4; ++k) {
            float4 x = *(const float4*)&tile[(w * 8 + tsub * 4 + k) * HH + h4 * 4];
            float p0 = k == 0 ? ep[0].x : k == 1 ? ep[0].y : k == 2 ? ep[0].z : ep[0].w;
            float p1 = k == 0 ? ep[1].x : k == 1 ? ep[1].y : k == 2 ? ep[1].z : ep[1].w;
            float p2 = k == 0 ? ep[2].x : k == 1 ? ep[2].y : k == 2 ? ep[2].z : ep[2].w;
            float p3 = k == 0 ? ep[3].x : k == 1 ? ep[3].y : k == 2 ? ep[3].z : ep[3].w;
            acc4[0].x = fmaf(p0, x.x, acc4[0].x); acc4[0].y = fmaf(p0, x.y, acc4[0].y);
            acc4[0].z = fmaf(p0, x.z, acc4[0].z); acc4[0].w = fmaf(p0, x.w, acc4[0].w);
            acc4[1].x = fmaf(p1, x.x, acc4[1].x); acc4[1].y = fmaf(p1, x.y, acc4[1].y);
            acc4[1].z = fmaf(p1, x.z, acc4[1].z); acc4[1].w = fmaf(p1, x.w, acc4[1].w);
            acc4[2].x = fmaf(p2, x.x, acc4[2].x); acc4[2].y = fmaf(p2, x.y, acc4[2].y);
            acc4[2].z = fmaf(p2, x.z, acc4[2].z); acc4[2].w = fmaf(p2, x.w, acc4[2].w);
            acc4[3].x = fmaf(p3, x.x, acc4[3].x); acc4[3].y = fmaf(p3, x.y, acc4[3].y);
            acc4[3].z = fmaf(p3, x.z, acc4[3].z); acc4[3].w = fmaf(p3, x.w, acc4[3].w);
        }
        __syncthreads();
    }

    // Combine tsub halves, park per-wave partials, tree-reduce across waves.
    #pragma unroll
    for (int d = 0; d < DTILE; ++d) {
        acc4[d].x += __shfl_xor(acc4[d].x, 32);
        acc4[d].y += __shfl_xor(acc4[d].y, 32);
        acc4[d].z += __shfl_xor(acc4[d].z, 32);
        acc4[d].w += __shfl_xor(acc4[d].w, 32);
    }
    if (tsub == 0) {
        #pragma unroll
        for (int d = 0; d < DTILE; ++d)
            *(float4*)&c_red[(w * DTILE + d) * HH + h4 * 4] = acc4[d];
    }
    __syncthreads();

    if (w < DTILE && l < 32) {
        float4 o = make_float4(0.f, 0.f, 0.f, 0.f);
        #pragma unroll
        for (int ww = 0; ww < 8; ++ww) {
            float4 p = *(const float4*)&c_red[(ww * DTILE + w) * HH + l * 4];
            o.x += p.x; o.y += p.y; o.z += p.z; o.w += p.w;
        }
        *(float4*)&c_out[((size_t)b * TD + d0 + w) * HH + l * 4] = o;
    }
}

// ---------------------------------------------------------------------------
extern "C" void kernel_launch(void* const* d_in, const int* in_sizes, int n_in,
                              void* d_out, int out_size, void* d_ws, size_t ws_size,
                              hipStream_t stream) {
    (void)in_sizes; (void)n_in; (void)out_size; (void)ws_size;

    const float* enc = (const float*)d_in[0];
    const float* dec = (const float*)d_in[1];
    const float* Wa  = (const float*)d_in[2];
    const float* Ua  = (const float*)d_in[3];
    const float* Va  = (const float*)d_in[4];

    float* c_out = (float*)d_out;
    float* e_out = (float*)d_out + BB * TD * HH;

    float* proj = (float*)d_ws;
    float* ws_p = proj;                  // C2*W_s: [B*TE, H]
    float* uh_p = proj + BB * TE * HH;   // C2*U_h: [B*TD, H]

    proj_gemm<<<192, 256, 0, stream>>>(enc, dec, Wa, Ua, proj);
    attn_fused<<<(BB * TD) / DTILE, 512, 0, stream>>>(enc, ws_p, uh_p, Va, c_out, e_out);
}

// Round 5
// 145.692 us; speedup vs baseline: 1.3532x; 1.0581x over previous
//
#include <hip/hip_runtime.h>

#define BB    4
#define TE    1024
#define TD    512
#define HH    128
#define DTILE 4
#define TTILE 64
#define C2    2.8853900817779268f   // 2*log2(e); proj pre-scales W_s and U_h by this
#define LOG2E 1.4426950408889634f

// Async global->LDS, 16B per lane. LDS dest = wave-uniform base + lane*16.
__device__ __forceinline__ void gload16_lds(const float* g, float* l) {
    __builtin_amdgcn_global_load_lds(
        (const __attribute__((address_space(1))) unsigned int*)g,
        (__attribute__((address_space(3))) unsigned int*)l, 16, 0, 0);
}

__device__ __forceinline__ float sigsum4(float4 wv, float4 cu, float4 v, float acc) {
    // acc += sum_i v_i * 1/(1 + 2^(wv_i + cu_i))   [inputs pre-scaled by C2]
    acc = fmaf(v.x, __builtin_amdgcn_rcpf(1.0f + __builtin_amdgcn_exp2f(wv.x + cu.x)), acc);
    acc = fmaf(v.y, __builtin_amdgcn_rcpf(1.0f + __builtin_amdgcn_exp2f(wv.y + cu.y)), acc);
    acc = fmaf(v.z, __builtin_amdgcn_rcpf(1.0f + __builtin_amdgcn_exp2f(wv.z + cu.z)), acc);
    acc = fmaf(v.w, __builtin_amdgcn_rcpf(1.0f + __builtin_amdgcn_exp2f(wv.w + cu.w)), acc);
    return acc;
}

// ---------------------------------------------------------------------------
// Kernel 1: tiled projections, output pre-scaled by C2 (unchanged).
// ---------------------------------------------------------------------------
__global__ __launch_bounds__(256) void proj_gemm(
    const float* __restrict__ enc, const float* __restrict__ dec,
    const float* __restrict__ Wa,  const float* __restrict__ Ua,
    float* __restrict__ out)
{
    __shared__ float Xs[64 * 33];
    __shared__ float Ws[32 * 64];

    const int tid = threadIdx.x;
    const int rt = blockIdx.x >> 1, ch = blockIdx.x & 1;
    const int r0 = rt * 64, c0 = ch * 64;

    const float* X; const float* W; int rX0;
    if (r0 < BB * TE) { X = enc; W = Wa; rX0 = r0; }
    else              { X = dec; W = Ua; rX0 = r0 - BB * TE; }

    const int c4 = tid & 15;
    const int rg = tid >> 4;

    float4 a0 = {0,0,0,0}, a1 = a0, a2 = a0, a3 = a0;

    for (int kc = 0; kc < 4; ++kc) {
        #pragma unroll
        for (int i = 0; i < 2; ++i) {
            int idx = tid + i * 256;
            int r  = idx >> 3, k4 = idx & 7;
            *(float4*)&Xs[r * 33 + k4 * 4] =
                *(const float4*)&X[(rX0 + r) * HH + kc * 32 + k4 * 4];
            int kk = idx >> 4, cc = idx & 15;
            *(float4*)&Ws[kk * 64 + cc * 4] =
                *(const float4*)&W[(kc * 32 + kk) * HH + c0 + cc * 4];
        }
        __syncthreads();
        #pragma unroll 8
        for (int k = 0; k < 32; ++k) {
            float4 wv = *(const float4*)&Ws[k * 64 + c4 * 4];
            float x0 = Xs[(rg * 4 + 0) * 33 + k];
            float x1 = Xs[(rg * 4 + 1) * 33 + k];
            float x2 = Xs[(rg * 4 + 2) * 33 + k];
            float x3 = Xs[(rg * 4 + 3) * 33 + k];
            a0.x = fmaf(x0, wv.x, a0.x); a0.y = fmaf(x0, wv.y, a0.y);
            a0.z = fmaf(x0, wv.z, a0.z); a0.w = fmaf(x0, wv.w, a0.w);
            a1.x = fmaf(x1, wv.x, a1.x); a1.y = fmaf(x1, wv.y, a1.y);
            a1.z = fmaf(x1, wv.z, a1.z); a1.w = fmaf(x1, wv.w, a1.w);
            a2.x = fmaf(x2, wv.x, a2.x); a2.y = fmaf(x2, wv.y, a2.y);
            a2.z = fmaf(x2, wv.z, a2.z); a2.w = fmaf(x2, wv.w, a2.w);
            a3.x = fmaf(x3, wv.x, a3.x); a3.y = fmaf(x3, wv.y, a3.y);
            a3.z = fmaf(x3, wv.z, a3.z); a3.w = fmaf(x3, wv.w, a3.w);
        }
        __syncthreads();
    }

    float4 accs[4] = {a0, a1, a2, a3};
    #pragma unroll
    for (int j = 0; j < 4; ++j) {
        float4 o = accs[j];
        o.x *= C2; o.y *= C2; o.z *= C2; o.w *= C2;
        *(float4*)&out[(r0 + rg * 4 + j) * HH + c0 + c4 * 4] = o;
    }
}

// ---------------------------------------------------------------------------
// Kernel 2: fused energies -> softmax -> context. Barrier-free main loops
// with per-wave DOUBLE-BUFFERED 8-row slabs (DMA prefetch targets the other
// buffer; sched_barrier(0) pins cross-iteration order), s_waitcnt vmcnt(4)
// pipelining. LDS = 64 KB tile dbuf + 16 KB e_s = 80 KB -> 2 blocks/CU.
// ---------------------------------------------------------------------------
__global__ __launch_bounds__(512, 4) void attn_fused(
    const float* __restrict__ enc,    // [B, TE, H] raw
    const float* __restrict__ ws,     // [B*TE, H]  = C2 * W_s
    const float* __restrict__ uh,     // [B*TD, H]  = C2 * U_h
    const float* __restrict__ Va,     // [H]
    float* __restrict__ c_out,        // [B, TD, H]
    float* __restrict__ e_out)        // [B, TD, TE]
{
    __shared__ float tile[8 * 2048];  // 8 waves x (2 bufs x 1024 floats) = 64 KB
    __shared__ float e_s[DTILE * TE]; // 16 KB

    const int tid = threadIdx.x;
    const int l   = tid & 63;
    const int w   = tid >> 6;            // 0..7 (row-octet owner)
    const int b   = blockIdx.x >> 7;
    const int d0  = (blockIdx.x & 127) * DTILE;

    const int c8 = l & 7;                // h-chunk selector / reduce dim
    const int r8 = l >> 3;               // row within octet

    float* slab = &tile[w * 2048];       // wave-private: buf p at slab + p*1024

    // Register fragments straight from global (L2-resident; no LDS round-trip)
    float4 cu4[DTILE][4], v4[4];
    #pragma unroll
    for (int j = 0; j < 4; ++j) {
        v4[j] = *(const float4*)&Va[(j * 8 + c8) * 4];
        #pragma unroll
        for (int d = 0; d < DTILE; ++d)
            cu4[d][j] = *(const float4*)&uh[((size_t)b * TD + d0 + d) * HH + (j * 8 + c8) * 4];
    }
    float Vsum = 0.f;
    #pragma unroll
    for (int j = 0; j < 4; ++j) Vsum += v4[j].x + v4[j].y + v4[j].z + v4[j].w;
    Vsum += __shfl_xor(Vsum, 1);
    Vsum += __shfl_xor(Vsum, 2);
    Vsum += __shfl_xor(Vsum, 4);

    const float* ws_w  = ws  + (size_t)b * TE * HH + w * 8 * HH;
    const float* enc_w = enc + (size_t)b * TE * HH + w * 8 * HH;

    // ---------------- Phase 1: energies (pipelined, barrier-free) ----------
    auto p1c = [&](int tt, const float* buf) {
        float acc[DTILE] = {0.f, 0.f, 0.f, 0.f};
        #pragma unroll
        for (int j = 0; j < 4; ++j) {
            float4 wv = *(const float4*)&buf[r8 * HH + (j * 8 + c8) * 4];
            #pragma unroll
            for (int d = 0; d < DTILE; ++d)
                acc[d] = sigsum4(wv, cu4[d][j], v4[j], acc[d]);
        }
        #pragma unroll
        for (int d = 0; d < DTILE; ++d) {
            acc[d] += __shfl_xor(acc[d], 1);
            acc[d] += __shfl_xor(acc[d], 2);
            acc[d] += __shfl_xor(acc[d], 4);
        }
        if (c8 == 0) {
            #pragma unroll
            for (int d = 0; d < DTILE; ++d)
                e_s[d * TE + tt * TTILE + w * 8 + r8] = Vsum - 2.f * acc[d];
        }
    };

    #pragma unroll
    for (int i = 0; i < 4; ++i)                       // prologue: tile 0 -> buf0
        gload16_lds(ws_w + i * 256 + l * 4, slab + i * 256);

    for (int tt = 0; tt < 15; ++tt) {
        const float* src = ws_w + (size_t)(tt + 1) * TTILE * HH;
        float* nb = slab + ((tt + 1) & 1) * 1024;
        #pragma unroll
        for (int i = 0; i < 4; ++i)
            gload16_lds(src + i * 256 + l * 4, nb + i * 256);
        __builtin_amdgcn_s_waitcnt(0x0F74);           // vmcnt(4): tile tt landed
        p1c(tt, slab + (tt & 1) * 1024);
        __builtin_amdgcn_sched_barrier(0);            // pin DMA(tt+2) after reads(tt)
    }
    __builtin_amdgcn_s_waitcnt(0x0F70);               // vmcnt(0)
    p1c(15, slab + 1024);

    __syncthreads();   // all waves' raw energies visible

    // ---------------- Phase 2: softmax (d = w&3, two waves split halves) ----
    {
        const int d2 = w & 3, hf = w >> 2;
        float ev[16];
        float m = -3.0e38f;
        #pragma unroll
        for (int i = 0; i < 16; ++i) {
            ev[i] = e_s[d2 * TE + i * 64 + l];
            m = fmaxf(m, ev[i]);
        }
        #pragma unroll
        for (int off = 32; off; off >>= 1) m = fmaxf(m, __shfl_xor(m, off));
        float s = 0.f;
        #pragma unroll
        for (int i = 0; i < 16; ++i) {
            ev[i] = __builtin_amdgcn_exp2f((ev[i] - m) * LOG2E);
            s += ev[i];
        }
        #pragma unroll
        for (int off = 32; off; off >>= 1) s += __shfl_xor(s, off);
        float inv = __builtin_amdgcn_rcpf(s);

        __syncthreads();   // all raw-energy reads done before overwrite
        float* eo = e_out + ((size_t)b * TD + d0 + d2) * TE;
        #pragma unroll
        for (int i = 0; i < 8; ++i) {
            int ii = hf * 8 + i;
            float p = ev[ii] * inv;
            e_s[d2 * TE + ii * 64 + l] = p;
            eo[ii * 64 + l] = p;
        }
        __syncthreads();   // normalized p visible to all waves
    }

    // ---------------- Phase 3: context (pipelined, barrier-free) ------------
    const int h4 = l & 31, tsub = l >> 5;
    float4 acc4[DTILE];
    #pragma unroll
    for (int d = 0; d < DTILE; ++d) acc4[d] = make_float4(0.f, 0.f, 0.f, 0.f);

    auto p3c = [&](int tt, const float* buf) {
        float4 ep[DTILE];
        #pragma unroll
        for (int d = 0; d < DTILE; ++d)
            ep[d] = *(const float4*)&e_s[d * TE + tt * TTILE + w * 8 + tsub * 4];
        #pragma unroll
        for (int k = 0; k < 4; ++k) {
            float4 x = *(const float4*)&buf[(tsub * 4 + k) * HH + h4 * 4];
            float p0 = k == 0 ? ep[0].x : k == 1 ? ep[0].y : k == 2 ? ep[0].z : ep[0].w;
            float p1 = k == 0 ? ep[1].x : k == 1 ? ep[1].y : k == 2 ? ep[1].z : ep[1].w;
            float p2 = k == 0 ? ep[2].x : k == 1 ? ep[2].y : k == 2 ? ep[2].z : ep[2].w;
            float p3 = k == 0 ? ep[3].x : k == 1 ? ep[3].y : k == 2 ? ep[3].z : ep[3].w;
            acc4[0].x = fmaf(p0, x.x, acc4[0].x); acc4[0].y = fmaf(p0, x.y, acc4[0].y);
            acc4[0].z = fmaf(p0, x.z, acc4[0].z); acc4[0].w = fmaf(p0, x.w, acc4[0].w);
            acc4[1].x = fmaf(p1, x.x, acc4[1].x); acc4[1].y = fmaf(p1, x.y, acc4[1].y);
            acc4[1].z = fmaf(p1, x.z, acc4[1].z); acc4[1].w = fmaf(p1, x.w, acc4[1].w);
            acc4[2].x = fmaf(p2, x.x, acc4[2].x); acc4[2].y = fmaf(p2, x.y, acc4[2].y);
            acc4[2].z = fmaf(p2, x.z, acc4[2].z); acc4[2].w = fmaf(p2, x.w, acc4[2].w);
            acc4[3].x = fmaf(p3, x.x, acc4[3].x); acc4[3].y = fmaf(p3, x.y, acc4[3].y);
            acc4[3].z = fmaf(p3, x.z, acc4[3].z); acc4[3].w = fmaf(p3, x.w, acc4[3].w);
        }
    };

    #pragma unroll
    for (int i = 0; i < 4; ++i)                       // prologue: tile 0 -> buf0
        gload16_lds(enc_w + i * 256 + l * 4, slab + i * 256);

    for (int tt = 0; tt < 15; ++tt) {
        const float* src = enc_w + (size_t)(tt + 1) * TTILE * HH;
        float* nb = slab + ((tt + 1) & 1) * 1024;
        #pragma unroll
        for (int i = 0; i < 4; ++i)
            gload16_lds(src + i * 256 + l * 4, nb + i * 256);
        __builtin_amdgcn_s_waitcnt(0x0F74);           // vmcnt(4)
        p3c(tt, slab + (tt & 1) * 1024);
        __builtin_amdgcn_sched_barrier(0);
    }
    __builtin_amdgcn_s_waitcnt(0x0F70);               // vmcnt(0)
    p3c(15, slab + 1024);

    // Combine tsub halves; park partials in tile (now dead); tree-reduce.
    #pragma unroll
    for (int d = 0; d < DTILE; ++d) {
        acc4[d].x += __shfl_xor(acc4[d].x, 32);
        acc4[d].y += __shfl_xor(acc4[d].y, 32);
        acc4[d].z += __shfl_xor(acc4[d].z, 32);
        acc4[d].w += __shfl_xor(acc4[d].w, 32);
    }
    __syncthreads();   // all waves done READING tile before we overwrite it
    float* c_red = tile;   // 8 waves x DTILE x HH = 16 KB <= 64 KB
    if (tsub == 0) {
        #pragma unroll
        for (int d = 0; d < DTILE; ++d)
            *(float4*)&c_red[(w * DTILE + d) * HH + h4 * 4] = acc4[d];
    }
    __syncthreads();

    if (w < DTILE && l < 32) {
        float4 o = make_float4(0.f, 0.f, 0.f, 0.f);
        #pragma unroll
        for (int ww = 0; ww < 8; ++ww) {
            float4 p = *(const float4*)&c_red[(ww * DTILE + w) * HH + l * 4];
            o.x += p.x; o.y += p.y; o.z += p.z; o.w += p.w;
        }
        *(float4*)&c_out[((size_t)b * TD + d0 + w) * HH + l * 4] = o;
    }
}

// ---------------------------------------------------------------------------
extern "C" void kernel_launch(void* const* d_in, const int* in_sizes, int n_in,
                              void* d_out, int out_size, void* d_ws, size_t ws_size,
                              hipStream_t stream) {
    (void)in_sizes; (void)n_in; (void)out_size; (void)ws_size;

    const float* enc = (const float*)d_in[0];
    const float* dec = (const float*)d_in[1];
    const float* Wa  = (const float*)d_in[2];
    const float* Ua  = (const float*)d_in[3];
    const float* Va  = (const float*)d_in[4];

    float* c_out = (float*)d_out;
    float* e_out = (float*)d_out + BB * TD * HH;

    float* proj = (float*)d_ws;
    float* ws_p = proj;                  // C2*W_s: [B*TE, H]
    float* uh_p = proj + BB * TE * HH;   // C2*U_h: [B*TD, H]

    proj_gemm<<<192, 256, 0, stream>>>(enc, dec, Wa, Ua, proj);
    attn_fused<<<(BB * TD) / DTILE, 512, 0, stream>>>(enc, ws_p, uh_p, Va, c_out, e_out);
}